// Round 9
// baseline (1194.973 us; speedup 1.0000x reference)
//
#include <hip/hip_runtime.h>
#include <hip/hip_bf16.h>
#include <cstdint>

// DTYPE CONTRACT (r5-r7 evidence):
//   device INPUTS  = float32  (f32-as-bf16 misread gave NaN, r5; npz size ~ f32)
//   device OUTPUT  = float32  (reference output dtype; r6/r7 identical absmax
//     4.140625 across two different GEMMs = deterministic format bug: we wrote
//     bf16 into an f32 buffer. Test label "(bf16,...)" is a hardcoded string.)
// Internal compute: bf16 MFMA with f32 accumulate.

// ---------- types / helpers ----------
using bf16x8 = __attribute__((ext_vector_type(8))) short;
using f32x4  = __attribute__((ext_vector_type(4))) float;

#define AS1C(p) ((const __attribute__((address_space(1))) void*)(p))
#define AS3(p)  ((__attribute__((address_space(3))) void*)(p))

__device__ __forceinline__ float bf2f(unsigned short u) {
  return __uint_as_float(((unsigned int)u) << 16);
}
__device__ __forceinline__ unsigned short f2bf(float f) {
  __hip_bfloat16 h = __float2bfloat16(f);   // RNE
  return *reinterpret_cast<unsigned short*>(&h);
}
__device__ __forceinline__ unsigned int pack2(float lo, float hi) {
  return (unsigned int)f2bf(lo) | ((unsigned int)f2bf(hi) << 16);
}

// ---------- f32 -> bf16 bulk convert (8 elems/thread, grid-stride) ----------
__global__ void cvt_k(const float* __restrict__ in, unsigned short* __restrict__ out,
                      size_t n8) {
  size_t i = (size_t)blockIdx.x * blockDim.x + threadIdx.x;
  size_t stride = (size_t)gridDim.x * blockDim.x;
  for (; i < n8; i += stride) {
    const float4* p = (const float4*)(in + i * 8);
    float4 a = p[0], b = p[1];
    uint4 o;
    o.x = pack2(a.x, a.y);
    o.y = pack2(a.z, a.w);
    o.z = pack2(b.x, b.y);
    o.w = pack2(b.z, b.w);
    ((uint4*)out)[i] = o;
  }
}

// ---------- weight transpose + convert: f32 in[R][C] -> bf16 out[C][R] ----------
__global__ void transpose_k(const float* __restrict__ in,
                            unsigned short* __restrict__ out, int R, int C) {
  __shared__ unsigned short tile[32][33];
  int c0 = blockIdx.x * 32, r0 = blockIdx.y * 32;
  int tx = threadIdx.x & 31, ty = threadIdx.x >> 5;  // 256 threads: ty 0..7
  #pragma unroll
  for (int i = ty; i < 32; i += 8) {
    int r = r0 + i, c = c0 + tx;
    tile[i][tx] = (r < R && c < C) ? f2bf(in[(size_t)r * C + c]) : (unsigned short)0;
  }
  __syncthreads();
  #pragma unroll
  for (int i = ty; i < 32; i += 8) {
    int c = c0 + i, r = r0 + tx;
    if (c < C && r < R) out[(size_t)c * R + r] = tile[tx][i];
  }
}

// ---------- GEMM: C[M][N] = A[M][K] * Bt[N][K]^T (+f32 bias) ----------
// bf16 inputs; OUT_F32 selects f32 (final, d_out) vs bf16 (intermediates) store.
// m97 structure: 128x128 tile, BK=64, 4 waves, global_load_lds width 16, 2 barriers.
// T1: XCD-aware bijective block swizzle when nwg % 8 == 0 (correctness-neutral).
#define BM 128
#define BN 128
#define BKK 64

template <bool OUT_F32>
__global__ __launch_bounds__(256) void gemm_bt_k(
    const unsigned short* __restrict__ A,
    const unsigned short* __restrict__ Bt,
    void* __restrict__ Cv,
    const float* __restrict__ bias,
    int M, int N, int K, int has_bias)
{
  __shared__ short sA[BM * BKK];
  __shared__ short sB[BN * BKK];
  const int tid = threadIdx.x;
  const int wid = tid >> 6, lane = tid & 63;

  // XCD swizzle (bijective when nwg divisible by 8; else identity)
  int nwg = gridDim.x * gridDim.y;
  int lin = blockIdx.y * gridDim.x + blockIdx.x;
  if ((nwg & 7) == 0) {
    int cpx = nwg >> 3;
    lin = (lin & 7) * cpx + (lin >> 3);
  }
  const int m0 = (lin % gridDim.x) * BM;
  const int n0 = (lin / gridDim.x) * BN;

  const int wr = wid >> 1, wc = wid & 1;
  const int l15 = lane & 15, l4 = lane >> 4;

  f32x4 acc[4][4];
  #pragma unroll
  for (int i = 0; i < 4; ++i)
    #pragma unroll
    for (int j = 0; j < 4; ++j)
      acc[i][j] = (f32x4){0.f, 0.f, 0.f, 0.f};

  for (int k0 = 0; k0 < K; k0 += BKK) {
    // stage A and B tiles: each wave fills contiguous 4KB chunks, lane*16B linear
    #pragma unroll
    for (int c = 0; c < 4; ++c) {
      int li  = wid * 256 + c * 64 + lane;     // 0..1023 linear 16B chunk id
      int row = li >> 3, col = (li & 7) * 8;   // row 0..127, col 0..56
      int gm = m0 + row; if (gm >= M) gm = M - 1;
      const unsigned short* gp = A + (size_t)gm * K + (k0 + col);
      __builtin_amdgcn_global_load_lds(AS1C(gp), AS3(sA + wid * 2048 + c * 512), 16, 0, 0);
      int gn = n0 + row; if (gn >= N) gn = N - 1;
      const unsigned short* gq = Bt + (size_t)gn * K + (k0 + col);
      __builtin_amdgcn_global_load_lds(AS1C(gq), AS3(sB + wid * 2048 + c * 512), 16, 0, 0);
    }
    __syncthreads();  // compiler drains vmcnt(0) before barrier

    #pragma unroll
    for (int kk = 0; kk < 2; ++kk) {
      bf16x8 af[4], bfg[4];
      #pragma unroll
      for (int i = 0; i < 4; ++i) {
        int r = wr * 64 + i * 16 + l15;
        af[i] = *(const bf16x8*)(sA + r * BKK + kk * 32 + l4 * 8);
      }
      #pragma unroll
      for (int j = 0; j < 4; ++j) {
        int cc = wc * 64 + j * 16 + l15;
        bfg[j] = *(const bf16x8*)(sB + cc * BKK + kk * 32 + l4 * 8);
      }
      #pragma unroll
      for (int i = 0; i < 4; ++i)
        #pragma unroll
        for (int j = 0; j < 4; ++j)
          acc[i][j] = __builtin_amdgcn_mfma_f32_16x16x32_bf16(af[i], bfg[j], acc[i][j], 0, 0, 0);
    }
    __syncthreads();  // protect LDS before next stage
  }

  // epilogue: C/D layout col=lane&15, row=(lane>>4)*4+v
  #pragma unroll
  for (int i = 0; i < 4; ++i) {
    #pragma unroll
    for (int j = 0; j < 4; ++j) {
      int n = n0 + wc * 64 + j * 16 + l15;
      float bv = has_bias ? bias[n] : 0.f;
      #pragma unroll
      for (int v = 0; v < 4; ++v) {
        int r = m0 + wr * 64 + i * 16 + l4 * 4 + v;
        if (r < M) {
          float val = acc[i][j][v] + bv;
          if (OUT_F32) ((float*)Cv)[(size_t)r * N + n] = val;
          else ((unsigned short*)Cv)[(size_t)r * N + n] = f2bf(val);
        }
      }
    }
  }
}

// ---------- fused dual cross-attention (txt 77 keys + ip 5 keys) ----------
// out = softmax(QK_txt/8)V_txt + 3 * softmax(QK_ip/8)V_ip, per head, in-place over Q.
#define S_LEN 4096
#define HIDD 1280
#define NTXT 77
#define NIP  5

__global__ __launch_bounds__(128) void attn_fuse_k(
    const unsigned short* Q,               // [B,S,HID] (also aliased by HS)
    const unsigned short* __restrict__ Kt, // [B,77,HID]
    const unsigned short* __restrict__ Vt,
    const unsigned short* __restrict__ Ki, // [B,5,HID]
    const unsigned short* __restrict__ Vi,
    unsigned short* HS)
{
  __shared__ float sK[NTXT * 64];
  __shared__ float sV[NTXT * 64];
  __shared__ float sKi[NIP * 64];
  __shared__ float sVi[NIP * 64];
  const int b = blockIdx.z, h = blockIdx.y;
  const int tid = threadIdx.x;

  for (int idx = tid; idx < NTXT * 64; idx += 128) {
    int t = idx >> 6, d = idx & 63;
    size_t g = ((size_t)b * NTXT + t) * HIDD + h * 64 + d;
    sK[idx] = bf2f(Kt[g]);
    sV[idx] = bf2f(Vt[g]);
  }
  for (int idx = tid; idx < NIP * 64; idx += 128) {
    int t = idx >> 6, d = idx & 63;
    size_t g = ((size_t)b * NIP + t) * HIDD + h * 64 + d;
    sKi[idx] = bf2f(Ki[g]);
    sVi[idx] = bf2f(Vi[g]);
  }
  __syncthreads();

  const int s = blockIdx.x * 128 + tid;
  const size_t qoff = ((size_t)b * S_LEN + s) * HIDD + h * 64;
  float q[64];
  const uint4* qp = (const uint4*)(Q + qoff);
  #pragma unroll
  for (int c = 0; c < 8; ++c) {
    uint4 v = qp[c];
    q[c*8+0] = __uint_as_float(v.x << 16);
    q[c*8+1] = __uint_as_float(v.x & 0xffff0000u);
    q[c*8+2] = __uint_as_float(v.y << 16);
    q[c*8+3] = __uint_as_float(v.y & 0xffff0000u);
    q[c*8+4] = __uint_as_float(v.z << 16);
    q[c*8+5] = __uint_as_float(v.z & 0xffff0000u);
    q[c*8+6] = __uint_as_float(v.w << 16);
    q[c*8+7] = __uint_as_float(v.w & 0xffff0000u);
  }

  float out[64];
  #pragma unroll
  for (int d = 0; d < 64; ++d) out[d] = 0.f;

  // text branch: scores are O(+-3) -> direct exp (softmax is shift-invariant)
  float sum = 0.f;
  for (int j = 0; j < NTXT; ++j) {
    const float* kj = sK + j * 64;
    float sc = 0.f;
    #pragma unroll
    for (int d = 0; d < 64; ++d) sc += q[d] * kj[d];
    float p = __expf(sc * 0.125f);
    sum += p;
    const float* vj = sV + j * 64;
    #pragma unroll
    for (int d = 0; d < 64; ++d) out[d] += p * vj[d];
  }
  float inv = 1.f / sum;
  #pragma unroll
  for (int d = 0; d < 64; ++d) out[d] *= inv;

  // ip branch, fused with coefficient (SCALE_IP + 1) = 3
  float pi[NIP];
  float sip = 0.f;
  #pragma unroll
  for (int j = 0; j < NIP; ++j) {
    const float* kj = sKi + j * 64;
    float sc = 0.f;
    #pragma unroll
    for (int d = 0; d < 64; ++d) sc += q[d] * kj[d];
    pi[j] = __expf(sc * 0.125f);
    sip += pi[j];
  }
  float inv3 = 3.f / sip;
  #pragma unroll
  for (int j = 0; j < NIP; ++j) {
    float w = pi[j] * inv3;
    const float* vj = sVi + j * 64;
    #pragma unroll
    for (int d = 0; d < 64; ++d) out[d] += w * vj[d];
  }

  uint4* op = (uint4*)(HS + qoff);
  #pragma unroll
  for (int c = 0; c < 8; ++c) {
    uint4 v;
    v.x = pack2(out[c*8+0], out[c*8+1]);
    v.y = pack2(out[c*8+2], out[c*8+3]);
    v.z = pack2(out[c*8+4], out[c*8+5]);
    v.w = pack2(out[c*8+6], out[c*8+7]);
    op[c] = v;
  }
}

// ---------- launch ----------
extern "C" void kernel_launch(void* const* d_in, const int* in_sizes, int n_in,
                              void* d_out, int out_size, void* d_ws, size_t ws_size,
                              hipStream_t stream)
{
  // INPUTS f32; OUTPUT f32.
  const float* X   = (const float*)d_in[0];  // [8,4096,1280]
  const float* ENC = (const float*)d_in[1];  // [8,77,768]
  const float* IP  = (const float*)d_in[2];  // [8,5,768]
  const float* Wq  = (const float*)d_in[3];  // [1280,1280]
  const float* Wk  = (const float*)d_in[4];  // [768,1280]
  const float* Wv  = (const float*)d_in[5];
  const float* Wki = (const float*)d_in[6];
  const float* Wvi = (const float*)d_in[7];
  const float* Wo  = (const float*)d_in[8];  // [1280,1280]
  const float* bo  = (const float*)d_in[9];  // [1280]

  char* ws = (char*)d_ws;
  size_t off = 0;
  auto alloc = [&](size_t elems) {
    unsigned short* p = (unsigned short*)(ws + off);
    off += ((elems * 2 + 255) & ~(size_t)255);
    return p;
  };
  unsigned short* WqT  = alloc((size_t)1280 * 1280);
  unsigned short* WoT  = alloc((size_t)1280 * 1280);
  unsigned short* WkT  = alloc((size_t)1280 * 768);
  unsigned short* WvT  = alloc((size_t)1280 * 768);
  unsigned short* WkiT = alloc((size_t)1280 * 768);
  unsigned short* WviT = alloc((size_t)1280 * 768);
  unsigned short* Ktxt = alloc((size_t)8 * 77 * 1280);
  unsigned short* Vtxt = alloc((size_t)8 * 77 * 1280);
  unsigned short* Kip  = alloc((size_t)8 * 5 * 1280);
  unsigned short* Vip  = alloc((size_t)8 * 5 * 1280);
  unsigned short* Xb   = alloc((size_t)8 * 4096 * 1280);  // bf16 copy of X
  unsigned short* ENCb = alloc((size_t)8 * 77 * 768);
  unsigned short* IPb  = alloc((size_t)8 * 5 * 768);
  unsigned short* Qb   = alloc((size_t)8 * 4096 * 1280);  // Q, then HS in-place

  // f32 -> bf16 activations
  size_t nX8 = (size_t)8 * 4096 * 1280 / 8;   // 5,242,880
  cvt_k<<<2048, 256, 0, stream>>>(X, Xb, nX8);
  size_t nE8 = (size_t)8 * 77 * 768 / 8;      // 59,136
  cvt_k<<<(int)((nE8 + 255) / 256), 256, 0, stream>>>(ENC, ENCb, nE8);
  size_t nI8 = (size_t)8 * 5 * 768 / 8;       // 3,840
  cvt_k<<<(int)((nI8 + 255) / 256), 256, 0, stream>>>(IP, IPb, nI8);

  // weights -> bf16 [N][K] so the MFMA B-operand reads contiguous K
  transpose_k<<<dim3(40, 40), 256, 0, stream>>>(Wq,  WqT,  1280, 1280);
  transpose_k<<<dim3(40, 40), 256, 0, stream>>>(Wo,  WoT,  1280, 1280);
  transpose_k<<<dim3(40, 24), 256, 0, stream>>>(Wk,  WkT,   768, 1280);
  transpose_k<<<dim3(40, 24), 256, 0, stream>>>(Wv,  WvT,   768, 1280);
  transpose_k<<<dim3(40, 24), 256, 0, stream>>>(Wki, WkiT,  768, 1280);
  transpose_k<<<dim3(40, 24), 256, 0, stream>>>(Wvi, WviT,  768, 1280);

  // projections (bf16 out to workspace)
  gemm_bt_k<false><<<dim3(256, 10), 256, 0, stream>>>(Xb,   WqT,  Qb,   bo, 32768, 1280, 1280, 0);
  gemm_bt_k<false><<<dim3(5, 10),   256, 0, stream>>>(ENCb, WkT,  Ktxt, bo,   616, 1280,  768, 0);
  gemm_bt_k<false><<<dim3(5, 10),   256, 0, stream>>>(ENCb, WvT,  Vtxt, bo,   616, 1280,  768, 0);
  gemm_bt_k<false><<<dim3(1, 10),   256, 0, stream>>>(IPb,  WkiT, Kip,  bo,    40, 1280,  768, 0);
  gemm_bt_k<false><<<dim3(1, 10),   256, 0, stream>>>(IPb,  WviT, Vip,  bo,    40, 1280,  768, 0);

  // fused dual attention + (txt + 3*ip), in-place over Qb
  attn_fuse_k<<<dim3(32, 20, 8), 128, 0, stream>>>(Qb, Ktxt, Vtxt, Kip, Vip, Qb);

  // output projection + bias -> FLOAT32 d_out
  gemm_bt_k<true><<<dim3(256, 10), 256, 0, stream>>>(Qb, WoT, d_out, bo,
                                                     32768, 1280, 1280, 1);
}

// Round 11
// 1119.685 us; speedup vs baseline: 1.0672x; 1.0672x over previous
//
#include <hip/hip_runtime.h>
#include <hip/hip_bf16.h>
#include <cstdint>

// DTYPE CONTRACT (r5-r9, VERIFIED r9 pass): inputs f32, output f32.
// Internal compute: bf16 MFMA with f32 accumulate. absmax 0.0156 vs thr 0.059.
//
// r9 profile: attn 410us (occupancy 15% - LDS-capped 2-wave blocks);
// GEMMs ~300us each (A re-fetched per n0-tile: m-fastest block mapping).
// r10: attn blocks 128->512 threads (same LDS -> 24 waves/CU);
//      GEMM n-fastest tile decomposition (A read ~once per XCD chunk).

// ---------- types / helpers ----------
using bf16x8 = __attribute__((ext_vector_type(8))) short;
using f32x4  = __attribute__((ext_vector_type(4))) float;

#define AS1C(p) ((const __attribute__((address_space(1))) void*)(p))
#define AS3(p)  ((__attribute__((address_space(3))) void*)(p))

__device__ __forceinline__ float bf2f(unsigned short u) {
  return __uint_as_float(((unsigned int)u) << 16);
}
__device__ __forceinline__ unsigned short f2bf(float f) {
  __hip_bfloat16 h = __float2bfloat16(f);   // RNE
  return *reinterpret_cast<unsigned short*>(&h);
}
__device__ __forceinline__ unsigned int pack2(float lo, float hi) {
  return (unsigned int)f2bf(lo) | ((unsigned int)f2bf(hi) << 16);
}

// ---------- f32 -> bf16 bulk convert (8 elems/thread, grid-stride) ----------
__global__ void cvt_k(const float* __restrict__ in, unsigned short* __restrict__ out,
                      size_t n8) {
  size_t i = (size_t)blockIdx.x * blockDim.x + threadIdx.x;
  size_t stride = (size_t)gridDim.x * blockDim.x;
  for (; i < n8; i += stride) {
    const float4* p = (const float4*)(in + i * 8);
    float4 a = p[0], b = p[1];
    uint4 o;
    o.x = pack2(a.x, a.y);
    o.y = pack2(a.z, a.w);
    o.z = pack2(b.x, b.y);
    o.w = pack2(b.z, b.w);
    ((uint4*)out)[i] = o;
  }
}

// ---------- weight transpose + convert: f32 in[R][C] -> bf16 out[C][R] ----------
__global__ void transpose_k(const float* __restrict__ in,
                            unsigned short* __restrict__ out, int R, int C) {
  __shared__ unsigned short tile[32][33];
  int c0 = blockIdx.x * 32, r0 = blockIdx.y * 32;
  int tx = threadIdx.x & 31, ty = threadIdx.x >> 5;  // 256 threads: ty 0..7
  #pragma unroll
  for (int i = ty; i < 32; i += 8) {
    int r = r0 + i, c = c0 + tx;
    tile[i][tx] = (r < R && c < C) ? f2bf(in[(size_t)r * C + c]) : (unsigned short)0;
  }
  __syncthreads();
  #pragma unroll
  for (int i = ty; i < 32; i += 8) {
    int c = c0 + i, r = r0 + tx;
    if (c < C && r < R) out[(size_t)c * R + r] = tile[tx][i];
  }
}

// ---------- GEMM: C[M][N] = A[M][K] * Bt[N][K]^T (+f32 bias) ----------
// bf16 inputs; OUT_F32 selects f32 (final, d_out) vs bf16 (intermediates) store.
// m97 structure: 128x128 tile, BK=64, 4 waves, global_load_lds width 16, 2 barriers.
// T1 XCD swizzle + n-fastest decomposition: an XCD's contiguous chunk walks all
// n-tiles of consecutive m-panels, so the streamed A panel is fetched ~once
// (B is small and L2-resident).
#define BM 128
#define BN 128
#define BKK 64

template <bool OUT_F32>
__global__ __launch_bounds__(256) void gemm_bt_k(
    const unsigned short* __restrict__ A,
    const unsigned short* __restrict__ Bt,
    void* __restrict__ Cv,
    const float* __restrict__ bias,
    int M, int N, int K, int has_bias)
{
  __shared__ short sA[BM * BKK];
  __shared__ short sB[BN * BKK];
  const int tid = threadIdx.x;
  const int wid = tid >> 6, lane = tid & 63;

  // XCD swizzle (bijective when nwg divisible by 8; else identity)
  int nwg = gridDim.x * gridDim.y;
  int lin = blockIdx.y * gridDim.x + blockIdx.x;
  if ((nwg & 7) == 0) {
    int cpx = nwg >> 3;
    lin = (lin & 7) * cpx + (lin >> 3);
  }
  // n-fastest: consecutive lin within an XCD chunk share the A m-panel
  const int NY = gridDim.y;               // # n-tiles
  const int m0 = (lin / NY) * BM;
  const int n0 = (lin % NY) * BN;

  const int wr = wid >> 1, wc = wid & 1;
  const int l15 = lane & 15, l4 = lane >> 4;

  f32x4 acc[4][4];
  #pragma unroll
  for (int i = 0; i < 4; ++i)
    #pragma unroll
    for (int j = 0; j < 4; ++j)
      acc[i][j] = (f32x4){0.f, 0.f, 0.f, 0.f};

  for (int k0 = 0; k0 < K; k0 += BKK) {
    // stage A and B tiles: each wave fills contiguous 4KB chunks, lane*16B linear
    #pragma unroll
    for (int c = 0; c < 4; ++c) {
      int li  = wid * 256 + c * 64 + lane;     // 0..1023 linear 16B chunk id
      int row = li >> 3, col = (li & 7) * 8;   // row 0..127, col 0..56
      int gm = m0 + row; if (gm >= M) gm = M - 1;
      const unsigned short* gp = A + (size_t)gm * K + (k0 + col);
      __builtin_amdgcn_global_load_lds(AS1C(gp), AS3(sA + wid * 2048 + c * 512), 16, 0, 0);
      int gn = n0 + row; if (gn >= N) gn = N - 1;
      const unsigned short* gq = Bt + (size_t)gn * K + (k0 + col);
      __builtin_amdgcn_global_load_lds(AS1C(gq), AS3(sB + wid * 2048 + c * 512), 16, 0, 0);
    }
    __syncthreads();  // compiler drains vmcnt(0) before barrier

    #pragma unroll
    for (int kk = 0; kk < 2; ++kk) {
      bf16x8 af[4], bfg[4];
      #pragma unroll
      for (int i = 0; i < 4; ++i) {
        int r = wr * 64 + i * 16 + l15;
        af[i] = *(const bf16x8*)(sA + r * BKK + kk * 32 + l4 * 8);
      }
      #pragma unroll
      for (int j = 0; j < 4; ++j) {
        int cc = wc * 64 + j * 16 + l15;
        bfg[j] = *(const bf16x8*)(sB + cc * BKK + kk * 32 + l4 * 8);
      }
      #pragma unroll
      for (int i = 0; i < 4; ++i)
        #pragma unroll
        for (int j = 0; j < 4; ++j)
          acc[i][j] = __builtin_amdgcn_mfma_f32_16x16x32_bf16(af[i], bfg[j], acc[i][j], 0, 0, 0);
    }
    __syncthreads();  // protect LDS before next stage
  }

  // epilogue: C/D layout col=lane&15, row=(lane>>4)*4+v
  #pragma unroll
  for (int i = 0; i < 4; ++i) {
    #pragma unroll
    for (int j = 0; j < 4; ++j) {
      int n = n0 + wc * 64 + j * 16 + l15;
      float bv = has_bias ? bias[n] : 0.f;
      #pragma unroll
      for (int v = 0; v < 4; ++v) {
        int r = m0 + wr * 64 + i * 16 + l4 * 4 + v;
        if (r < M) {
          float val = acc[i][j][v] + bv;
          if (OUT_F32) ((float*)Cv)[(size_t)r * N + n] = val;
          else ((unsigned short*)Cv)[(size_t)r * N + n] = f2bf(val);
        }
      }
    }
  }
}

// ---------- fused dual cross-attention (txt 77 keys + ip 5 keys) ----------
// out = softmax(QK_txt/8)V_txt + 3 * softmax(QK_ip/8)V_ip, per head, in-place over Q.
// r10: 512-thread blocks (8 waves) + 41984B LDS -> 3 blocks/CU = 24 waves/CU (75%).
#define S_LEN 4096
#define HIDD 1280
#define NTXT 77
#define NIP  5

__global__ __launch_bounds__(512) void attn_fuse_k(
    const unsigned short* Q,               // [B,S,HID] (also aliased by HS)
    const unsigned short* __restrict__ Kt, // [B,77,HID]
    const unsigned short* __restrict__ Vt,
    const unsigned short* __restrict__ Ki, // [B,5,HID]
    const unsigned short* __restrict__ Vi,
    unsigned short* HS)
{
  __shared__ float sK[NTXT * 64];
  __shared__ float sV[NTXT * 64];
  __shared__ float sKi[NIP * 64];
  __shared__ float sVi[NIP * 64];
  const int b = blockIdx.z, h = blockIdx.y;
  const int tid = threadIdx.x;

  for (int idx = tid; idx < NTXT * 64; idx += 512) {
    int t = idx >> 6, d = idx & 63;
    size_t g = ((size_t)b * NTXT + t) * HIDD + h * 64 + d;
    sK[idx] = bf2f(Kt[g]);
    sV[idx] = bf2f(Vt[g]);
  }
  if (tid < NIP * 64) {
    int t = tid >> 6, d = tid & 63;
    size_t g = ((size_t)b * NIP + t) * HIDD + h * 64 + d;
    sKi[tid] = bf2f(Ki[g]);
    sVi[tid] = bf2f(Vi[g]);
  }
  __syncthreads();

  const int s = blockIdx.x * 512 + tid;
  const size_t qoff = ((size_t)b * S_LEN + s) * HIDD + h * 64;
  float q[64];
  const uint4* qp = (const uint4*)(Q + qoff);
  #pragma unroll
  for (int c = 0; c < 8; ++c) {
    uint4 v = qp[c];
    q[c*8+0] = __uint_as_float(v.x << 16);
    q[c*8+1] = __uint_as_float(v.x & 0xffff0000u);
    q[c*8+2] = __uint_as_float(v.y << 16);
    q[c*8+3] = __uint_as_float(v.y & 0xffff0000u);
    q[c*8+4] = __uint_as_float(v.z << 16);
    q[c*8+5] = __uint_as_float(v.z & 0xffff0000u);
    q[c*8+6] = __uint_as_float(v.w << 16);
    q[c*8+7] = __uint_as_float(v.w & 0xffff0000u);
  }

  float out[64];
  #pragma unroll
  for (int d = 0; d < 64; ++d) out[d] = 0.f;

  // text branch: scores are O(+-3) -> direct exp (softmax is shift-invariant)
  float sum = 0.f;
  for (int j = 0; j < NTXT; ++j) {
    const float* kj = sK + j * 64;
    float sc = 0.f;
    #pragma unroll
    for (int d = 0; d < 64; ++d) sc += q[d] * kj[d];
    float p = __expf(sc * 0.125f);
    sum += p;
    const float* vj = sV + j * 64;
    #pragma unroll
    for (int d = 0; d < 64; ++d) out[d] += p * vj[d];
  }
  float inv = 1.f / sum;
  #pragma unroll
  for (int d = 0; d < 64; ++d) out[d] *= inv;

  // ip branch, fused with coefficient (SCALE_IP + 1) = 3
  float pi[NIP];
  float sip = 0.f;
  #pragma unroll
  for (int j = 0; j < NIP; ++j) {
    const float* kj = sKi + j * 64;
    float sc = 0.f;
    #pragma unroll
    for (int d = 0; d < 64; ++d) sc += q[d] * kj[d];
    pi[j] = __expf(sc * 0.125f);
    sip += pi[j];
  }
  float inv3 = 3.f / sip;
  #pragma unroll
  for (int j = 0; j < NIP; ++j) {
    float w = pi[j] * inv3;
    const float* vj = sVi + j * 64;
    #pragma unroll
    for (int d = 0; d < 64; ++d) out[d] += w * vj[d];
  }

  uint4* op = (uint4*)(HS + qoff);
  #pragma unroll
  for (int c = 0; c < 8; ++c) {
    uint4 v;
    v.x = pack2(out[c*8+0], out[c*8+1]);
    v.y = pack2(out[c*8+2], out[c*8+3]);
    v.z = pack2(out[c*8+4], out[c*8+5]);
    v.w = pack2(out[c*8+6], out[c*8+7]);
    op[c] = v;
  }
}

// ---------- launch ----------
extern "C" void kernel_launch(void* const* d_in, const int* in_sizes, int n_in,
                              void* d_out, int out_size, void* d_ws, size_t ws_size,
                              hipStream_t stream)
{
  // INPUTS f32; OUTPUT f32.
  const float* X   = (const float*)d_in[0];  // [8,4096,1280]
  const float* ENC = (const float*)d_in[1];  // [8,77,768]
  const float* IP  = (const float*)d_in[2];  // [8,5,768]
  const float* Wq  = (const float*)d_in[3];  // [1280,1280]
  const float* Wk  = (const float*)d_in[4];  // [768,1280]
  const float* Wv  = (const float*)d_in[5];
  const float* Wki = (const float*)d_in[6];
  const float* Wvi = (const float*)d_in[7];
  const float* Wo  = (const float*)d_in[8];  // [1280,1280]
  const float* bo  = (const float*)d_in[9];  // [1280]

  char* ws = (char*)d_ws;
  size_t off = 0;
  auto alloc = [&](size_t elems) {
    unsigned short* p = (unsigned short*)(ws + off);
    off += ((elems * 2 + 255) & ~(size_t)255);
    return p;
  };
  unsigned short* WqT  = alloc((size_t)1280 * 1280);
  unsigned short* WoT  = alloc((size_t)1280 * 1280);
  unsigned short* WkT  = alloc((size_t)1280 * 768);
  unsigned short* WvT  = alloc((size_t)1280 * 768);
  unsigned short* WkiT = alloc((size_t)1280 * 768);
  unsigned short* WviT = alloc((size_t)1280 * 768);
  unsigned short* Ktxt = alloc((size_t)8 * 77 * 1280);
  unsigned short* Vtxt = alloc((size_t)8 * 77 * 1280);
  unsigned short* Kip  = alloc((size_t)8 * 5 * 1280);
  unsigned short* Vip  = alloc((size_t)8 * 5 * 1280);
  unsigned short* Xb   = alloc((size_t)8 * 4096 * 1280);  // bf16 copy of X
  unsigned short* ENCb = alloc((size_t)8 * 77 * 768);
  unsigned short* IPb  = alloc((size_t)8 * 5 * 768);
  unsigned short* Qb   = alloc((size_t)8 * 4096 * 1280);  // Q, then HS in-place

  // f32 -> bf16 activations
  size_t nX8 = (size_t)8 * 4096 * 1280 / 8;   // 5,242,880
  cvt_k<<<2048, 256, 0, stream>>>(X, Xb, nX8);
  size_t nE8 = (size_t)8 * 77 * 768 / 8;      // 59,136
  cvt_k<<<(int)((nE8 + 255) / 256), 256, 0, stream>>>(ENC, ENCb, nE8);
  size_t nI8 = (size_t)8 * 5 * 768 / 8;       // 3,840
  cvt_k<<<(int)((nI8 + 255) / 256), 256, 0, stream>>>(IP, IPb, nI8);

  // weights -> bf16 [N][K] so the MFMA B-operand reads contiguous K
  transpose_k<<<dim3(40, 40), 256, 0, stream>>>(Wq,  WqT,  1280, 1280);
  transpose_k<<<dim3(40, 40), 256, 0, stream>>>(Wo,  WoT,  1280, 1280);
  transpose_k<<<dim3(40, 24), 256, 0, stream>>>(Wk,  WkT,   768, 1280);
  transpose_k<<<dim3(40, 24), 256, 0, stream>>>(Wv,  WvT,   768, 1280);
  transpose_k<<<dim3(40, 24), 256, 0, stream>>>(Wki, WkiT,  768, 1280);
  transpose_k<<<dim3(40, 24), 256, 0, stream>>>(Wvi, WviT,  768, 1280);

  // projections (bf16 out to workspace)
  gemm_bt_k<false><<<dim3(256, 10), 256, 0, stream>>>(Xb,   WqT,  Qb,   bo, 32768, 1280, 1280, 0);
  gemm_bt_k<false><<<dim3(5, 10),   256, 0, stream>>>(ENCb, WkT,  Ktxt, bo,   616, 1280,  768, 0);
  gemm_bt_k<false><<<dim3(5, 10),   256, 0, stream>>>(ENCb, WvT,  Vtxt, bo,   616, 1280,  768, 0);
  gemm_bt_k<false><<<dim3(1, 10),   256, 0, stream>>>(IPb,  WkiT, Kip,  bo,    40, 1280,  768, 0);
  gemm_bt_k<false><<<dim3(1, 10),   256, 0, stream>>>(IPb,  WviT, Vip,  bo,    40, 1280,  768, 0);

  // fused dual attention + (txt + 3*ip), in-place over Qb
  attn_fuse_k<<<dim3(8, 20, 8), 512, 0, stream>>>(Qb, Ktxt, Vtxt, Kip, Vip, Qb);

  // output projection + bias -> FLOAT32 d_out
  gemm_bt_k<true><<<dim3(256, 10), 256, 0, stream>>>(Qb, WoT, d_out, bo,
                                                     32768, 1280, 1280, 1);
}